// Round 5
// baseline (288.553 us; speedup 1.0000x reference)
//
#include <hip/hip_runtime.h>

#define B_SZ 256
#define P_SZ 128
#define F_SZ 7
#define H_SZ 256
#define KNB  16
#define CH_OUT 264   // H + F + 1

typedef __bf16 bf16x8 __attribute__((ext_vector_type(8)));
typedef __bf16 bf16x4 __attribute__((ext_vector_type(4)));
typedef float  f32x4  __attribute__((ext_vector_type(4)));
typedef float  f32x16 __attribute__((ext_vector_type(16)));

// ---------------------------------------------------------------------------
// Grid = 512: block (b, ph) handles batch b, points ph*64..+63. 8 waves.
// THIS ROUND: LDS 78 -> 46 KB -> 3 blocks/CU (24 waves/CU, 6/SIMD).
//   Round-4 analysis: no pipe above ~35% (LDS ~30%, VALU ~20%, MFMA ~8 us
//   static) -> latency-bound at 4 waves/SIMD. Fix = occupancy:
//   (a) 2 points/iter x 32 iters: sH1 buffer 16 KB, dbuf 32 KB (was 64).
//       Phase 1: 4 waves/point, 4 W1-tiles each. Phase 2: m=32 = 2 pts x
//       16 nbrs, one group per iter (work/point unchanged).
//   (b) KNN merge tree uses 4 list slots (32 KB, overlays dbuf exactly):
//       slots0-3 <- waves4-7; stage A republishes 1,3; B republishes 2.
//   launch_bounds(512,6) -> VGPR cap ~341, spill pressure gone.
// GEMM2 on mfma_f32_32x32x16_bf16 (m=2x16 stack, n=wave's 32-col slice).
// CRITICAL: every loop indexing per-lane arrays must be FULLY UNROLLED
//   (constant indices) or the compiler demotes to scratch.
//  KNN: 8-way split scan (16 cands/wave), tiered insert (8 then 16), Batcher
//    half-cleaner + bitonic merges, exact f64 keys -> exact top-16.
//  Main loop software-pipelined: ONE barrier/iter, phase1(it+1)->buf[!cur]
//    in the same window as phase2(it)<-buf[cur].
//  sW1 compressed to [16][32][8] (8 KB): rows 32..63 structural zeros; lanes
//    >=32 read sW1[tt][lane&31] (same-address broadcast, af==0 there).
//  sH1 chunk-major [pt][kc=k/8][nbr=16][8el]: phase-2 b128 reads conflict-
//    free, phase-1 b64 stores 2-way (free).
// ---------------------------------------------------------------------------
__global__ __launch_bounds__(512, 6) void edgeconv_fused(
    const float* __restrict__ ev, const float* __restrict__ W1,
    const float* __restrict__ b1, const float* __restrict__ W2,
    const float* __restrict__ b2, float* __restrict__ out) {
  const int b    = blockIdx.x >> 1;
  const int ph   = blockIdx.x & 1;
  const int tid  = threadIdx.x;
  const int lane = tid & 63;
  const int wave = tid >> 6;         // 0..7
  const int qd   = lane >> 4;        // 0..3
  const int c16  = lane & 15;

  __shared__ float sFeats[P_SZ][8];                     // 4 KB (full batch)
  __shared__ __align__(16) __bf16 sW1[16][32][8];       // 8 KB, k<16 half only
  __shared__ unsigned short sIdx[64][KNB];              // 2 KB (this block's pts)
  // union: 2 x sH1 double buffer (2 x 16384 B); KNN lists [4][16][64] f64
  // = 32768 B overlay exactly (disjoint lifetimes, barrier-separated).
  __shared__ __align__(16) unsigned char sU[2 * 16384];
  double* lists = (double*)sU;                          // [slot4][16][64]
  __bf16* buf0  = (__bf16*)sU;                          // sH1 buffer 0
  __bf16* buf1  = (__bf16*)(sU + 16384);                // sH1 buffer 1

  // ---- stage events + W1 frags (bias folded in at k=14; k<16 half only) ----
  if (tid < 2 * P_SZ)
    ((float4*)&sFeats[0][0])[tid] = ((const float4*)(ev + (size_t)b * P_SZ * 8))[tid];
  {   // 16 tiles x 32 rows (512 threads -> one each)
    const int t = tid >> 5, l32 = tid & 31;
    const int qq = l32 >> 4, cc = l32 & 15;
    const int n = t * 16 + cc;
    bf16x8 v;
#pragma unroll
    for (int j = 0; j < 8; ++j) {
      const int k = qq * 8 + j;
      float w = 0.0f;
      if (k < 2 * F_SZ) w = W1[k * H_SZ + n];
      else if (k == 2 * F_SZ) w = b1[n];   // bias row, edge supplies 1.0
      v[j] = (__bf16)w;
    }
    *(bf16x8*)&sW1[t][l32][0] = v;
  }
  __syncthreads();

  // ---- feats passthrough + mask channel (needs only sFeats) ----
  {
    const int pl = tid >> 3, ch = tid & 7;       // 64 pts x 8 ch
    const int pg = ph * 64 + pl;
    const float msk = sFeats[pg][7];
    float v;
    if (ch < 7) {
      float fv = sFeats[pg][ch];
      fv = fv > 0.0f ? fv : 0.2f * fv;
      v = (msk > 0.5f ? 1.0f : 0.0f) * fv;
    } else {
      v = msk;
    }
    out[((size_t)(b * P_SZ + pg)) * CH_OUT + H_SZ + ch] = v;
  }

  // ===================  KNN (f64 keys, bitonic merge tree)  =================
  // lane-point = ph*64 + lane; wave scans candidates wave*16..+15 (eighth).
  const int ip = ph * 64 + lane;
  const float xi = sFeats[ip][0], yi = sFeats[ip][1];

  double arr[16];
#pragma unroll
  for (int t = 0; t < 16; ++t) arr[t] = 1.0e300;

  // tiered sorted-insert scan: depth 8 for first 8 cands, depth 16 after.
#pragma unroll 1
  for (int cc = 0; cc < 8; ++cc) {
    const int j = wave * 16 + cc;              // wave-uniform -> LDS broadcast
    const float2 cj = *(const float2*)&sFeats[j][0];
    const float mj  = sFeats[j][7];
    const float dx = xi - cj.x, dy = yi - cj.y;
    const float d  = sqrtf(dx * dx + dy * dy);
    const float dd = (mj > 0.5f && j != ip) ? d : 3.0e38f;  // self excluded
    double key = (double)__float_as_uint(dd) * 128.0 + (double)j;  // exact
#pragma unroll
    for (int t = 0; t < 8; ++t) {
      const double lo = fmin(arr[t], key);
      key    = fmax(arr[t], key);
      arr[t] = lo;
    }
  }
#pragma unroll 1
  for (int cc = 8; cc < 16; ++cc) {
    const int j = wave * 16 + cc;
    const float2 cj = *(const float2*)&sFeats[j][0];
    const float mj  = sFeats[j][7];
    const float dx = xi - cj.x, dy = yi - cj.y;
    const float d  = sqrtf(dx * dx + dy * dy);
    const float dd = (mj > 0.5f && j != ip) ? d : 3.0e38f;
    double key = (double)__float_as_uint(dd) * 128.0 + (double)j;
#pragma unroll
    for (int t = 0; t < 16; ++t) {
      const double lo = fmin(arr[t], key);
      key    = fmax(arr[t], key);
      arr[t] = lo;
    }
  }

  // merge: half-cleaner (16 fmin) + 4-stage bitonic sort of bitonic seq.
  auto mergeList = [&](const double* src) {
    double oth[16];
#pragma unroll
    for (int t = 0; t < 16; ++t) oth[t] = src[t * 64 + lane];
#pragma unroll
    for (int t = 0; t < 16; ++t) arr[t] = fmin(arr[t], oth[15 - t]);
#pragma unroll
    for (int d = 8; d >= 1; d >>= 1) {
#pragma unroll
      for (int i = 0; i < 16; ++i) {
        if ((i & d) == 0) {
          const double lo = fmin(arr[i], arr[i + d]);
          arr[i + d] = fmax(arr[i], arr[i + d]);
          arr[i] = lo;
        }
      }
    }
  };
  auto publish = [&](int slot) {
#pragma unroll
    for (int t = 0; t < 16; ++t) lists[(slot * 16 + t) * 64 + lane] = arr[t];
  };

  if (wave >= 4) publish(wave - 4);      // slots 0..3 <- eighths 4..7
  __syncthreads();
  if (wave < 4) {                        // stage A: {w, w+4} (read own slot,
    mergeList(&lists[(wave * 16) * 64]); //  then overwrite it if needed)
    if (wave == 1 || wave == 3) publish(wave);
  }
  __syncthreads();
  if (wave == 0) mergeList(&lists[(1 * 16) * 64]);   // {0,1,4,5}
  if (wave == 2) {                                   // {2,3,6,7} -> slot 2
    mergeList(&lists[(3 * 16) * 64]);
    publish(2);
  }
  __syncthreads();
  if (wave == 0) {                       // stage C: full top-16, sorted asc
    mergeList(&lists[(2 * 16) * 64]);
#pragma unroll
    for (int t = 0; t < 16; ++t) {
      const unsigned long long kv = (unsigned long long)arr[t];
      sIdx[lane][t] = (unsigned short)(kv & 127);
    }
  }
  __syncthreads();   // sIdx ready; lists region free for sH1 buffers

  // ---- W2 B-fragments for 32x32x16: wave owns cols [wave*32, +32).
  // Per lane: col = wave*32 + (lane&31), k = kk*16 + (lane>>5)*8 + j.
  // 16 frags x 4 VGPR = 64 regs; loaded after KNN (arr/oth dead).
  const int wcol  = wave * 32 + (lane & 31);
  const int khalf = (lane >> 5) * 8;
  bf16x8 w2f[16];
#pragma unroll
  for (int kk = 0; kk < 16; ++kk) {
#pragma unroll
    for (int j = 0; j < 8; ++j)
      w2f[kk][j] = (__bf16)W2[(kk * 16 + khalf + j) * H_SZ + wcol];
  }
  const float b2v = b2[wcol];

  // ---- Phase 1 (transposed GEMM1) for iteration it1 into buffer sH1w ----
  // 2 points/iter: 4 waves per point, each wave does 4 of 16 W1 n-tiles.
  auto phase1 = [&](int it1, __bf16* __restrict__ sH1w) {
    const int pw = wave >> 2;              // which of the 2 points
    const int wq = wave & 3;               // W1-tile quarter
    const int pl = it1 * 2 + pw;           // local point 0..63
    const int pg = ph * 64 + pl;           // global row in sFeats
    const int nb = sIdx[pl][c16];
    const float* cf = &sFeats[pg][0];
    float4 nf0 = *(const float4*)&sFeats[nb][0];
    float4 nf1 = *(const float4*)&sFeats[nb][4];
    const float nfv[8] = {nf0.x, nf0.y, nf0.z, nf0.w, nf1.x, nf1.y, nf1.z, nf1.w};
    float ed[8];
    if (qd == 0) {        // k = 0..7: central[0..6], (neigh-central)[0]
#pragma unroll
      for (int j = 0; j < 7; ++j) ed[j] = cf[j];
      ed[7] = nfv[0] - cf[0];
    } else if (qd == 1) { // k = 8..15: (n-c)[1..6], bias-1.0 at k=14, pad
#pragma unroll
      for (int j = 0; j < 6; ++j) ed[j] = nfv[j + 1] - cf[j + 1];
      ed[6] = 1.0f; ed[7] = 0.0f;
    } else {              // k = 16..31: zero pad (lanes>=32 A-frag don't-care)
#pragma unroll
      for (int j = 0; j < 8; ++j) ed[j] = 0.0f;
    }
    bf16x8 af;
#pragma unroll
    for (int j = 0; j < 8; ++j) af[j] = (__bf16)ed[j];

#pragma unroll
    for (int t = 0; t < 4; ++t) {
      const int tt = wq * 4 + t;
      // lanes >=32: same-address broadcast read; value is don't-care (af==0)
      bf16x8 w1t = *(const bf16x8*)&sW1[tt][lane & 31][0];
      f32x4 acc = {0.0f, 0.0f, 0.0f, 0.0f};
      acc = __builtin_amdgcn_mfma_f32_16x16x32_bf16(w1t, af, acc, 0, 0, 0);
      bf16x4 hv;
#pragma unroll
      for (int rr = 0; rr < 4; ++rr) {
        float h = acc[rr];
        h = h > 0.0f ? h : 0.0f;
        hv[rr] = (__bf16)h;
      }
      // chunk-major: n = tt*16 + qd*4 + rr -> kc = tt*2 + (qd>>1), off = (qd&1)*4
      const int kc = tt * 2 + (qd >> 1);
      *(bf16x4*)&sH1w[(((size_t)pw * 32 + kc) * 16 + c16) * 8 + (qd & 1) * 4] = hv;
    }
  };

  // ---- Phase 2: both iter points stacked into m=32 ----
  // A-frag: m = lane&31 (pt=(lane>>4)&1, nbr=lane&15), kc = kk*2 + (lane>>5).
  // C/D: col = lane&31, row = (reg&3)+8*(reg>>2)+4*(lane>>5):
  //   pt0 rows 0..15 in regs 0..7 (split across lane halves),
  //   pt1 rows 16..31 in regs 8..15 -> one shfl_xor(32) per point-sum.
  auto phase2 = [&](int it2, const __bf16* __restrict__ sH1r) {
    f32x16 acc = {};
    const int app = (lane >> 4) & 1;
    const int anb = lane & 15;
    const int kho = lane >> 5;
#pragma unroll
    for (int kk = 0; kk < 16; ++kk) {
      const int kc = kk * 2 + kho;
      bf16x8 a = *(const bf16x8*)&sH1r[(((size_t)app * 32 + kc) * 16 + anb) * 8];
      acc = __builtin_amdgcn_mfma_f32_32x32x16_bf16(a, w2f[kk], acc, 0, 0, 0);
    }

    float sA = 0.0f, sB = 0.0f;
#pragma unroll
    for (int r = 0; r < 8; ++r) {
      const float h = acc[r] + b2v;
      sA += (h > 0.0f ? h : 0.0f);
    }
#pragma unroll
    for (int r = 8; r < 16; ++r) {
      const float h = acc[r] + b2v;
      sB += (h > 0.0f ? h : 0.0f);
    }
    sA += __shfl_xor(sA, 32, 64);       // combine the two lane-half row sets
    sB += __shfl_xor(sB, 32, 64);
    const int pi  = lane >> 5;          // lanes<32 store pt0, lanes>=32 pt1
    const float s = pi ? sB : sA;
    const int ptg = ph * 64 + it2 * 2 + pi;
    const float msk  = sFeats[ptg][7];
    const float keep = (msk > 0.5f) ? 1.0f : 0.0f;
    const float agg = s * (1.0f / 16.0f);
    const float o = agg > 0.0f ? agg : 0.2f * agg;
    out[((size_t)(b * P_SZ + ptg)) * CH_OUT + wave * 32 + (lane & 31)] = keep * o;
  };

  // =================  pipelined main loop: 1 barrier / iter  =================
  phase1(0, buf0);
  __syncthreads();
#pragma unroll 1
  for (int it = 0; it < 32; ++it) {
    const __bf16* rd = (it & 1) ? buf1 : buf0;
    __bf16* wr = (it & 1) ? buf0 : buf1;
    if (it < 31) phase1(it + 1, wr);   // produce next tile into other buffer
    phase2(it, rd);                    // consume current tile
    __syncthreads();                   // wr complete before next iter reads it
  }
}

// ---------------------------------------------------------------------------
extern "C" void kernel_launch(void* const* d_in, const int* in_sizes, int n_in,
                              void* d_out, int out_size, void* d_ws, size_t ws_size,
                              hipStream_t stream) {
  const float* ev = (const float*)d_in[0];
  const float* W1 = (const float*)d_in[1];
  const float* b1 = (const float*)d_in[2];
  const float* W2 = (const float*)d_in[3];
  const float* b2 = (const float*)d_in[4];
  float* out = (float*)d_out;

  edgeconv_fused<<<B_SZ * 2, 512, 0, stream>>>(ev, W1, b1, W2, b2, out);
}

// Round 6
// 206.361 us; speedup vs baseline: 1.3983x; 1.3983x over previous
//
#include <hip/hip_runtime.h>

#define B_SZ 256
#define P_SZ 128
#define F_SZ 7
#define H_SZ 256
#define KNB  16
#define CH_OUT 264   // H + F + 1

typedef __bf16 bf16x8 __attribute__((ext_vector_type(8)));
typedef __bf16 bf16x4 __attribute__((ext_vector_type(4)));
typedef float  f32x4  __attribute__((ext_vector_type(4)));
typedef float  f32x16 __attribute__((ext_vector_type(16)));

// ---------------------------------------------------------------------------
// Grid = 512: block (b, ph) handles batch b, points ph*64..+63. 8 waves.
// Geometry: launch_bounds(512,4) -> total-reg cap 128, 2 blocks/CU (verified
//   best; round 5 proved (512,6) CUTS the cap to ~80 -> w2f spills -> 250 us).
// Register wall (invariant): W2 full residency across 8 waves = 64 VGPR/wave
//   regardless of split; total liveness ~120 -> 4 waves/SIMD is the ceiling.
// Phase-2 is at the structural LDS minimum (1 A-read b128 per MFMA).
// THIS ROUND (overlap tuning at fixed geometry, bit-identical output):
//  * Phase-2 groups FUSED into one k-loop (accA/accB): 2 independent MFMA
//    chains, 32 A-reads batched -> deeper LDS queue. Epilogues split around
//    phase1 (epiA -> phase1 -> epiB) to keep peak regs ~114 < 128.
//  * Phase-1 neighbor gather predicated to qd<2 (lanes qd>=2 build zero
//    edges; their nfv is dead) -> halves random-row gather bank traffic.
//  * Final-iteration barrier skipped (dead).
// CRITICAL: every loop indexing per-lane arrays must be FULLY UNROLLED
//   (constant indices) or the compiler demotes to scratch.
//  KNN: 8-way split scan (16 cands/wave), tiered insert (8 then 16), Batcher
//    half-cleaner + bitonic merges, exact f64 keys -> exact top-16.
//  Main loop software-pipelined: sH1 double-buffered (2 x 32 KB), ONE barrier
//    per iteration: phase1(it+1)->buf[!cur] inside phase2(it)'s window.
//  sW1 compressed to [16][32][8] (8 KB): rows 32..63 structural zeros; lanes
//    >=32 read sW1[tt][lane&31] (same-address broadcast, af==0 there).
//  sH1 chunk-major [pt][kc=k/8][nbr=16][8el]: phase-2 b128 reads conflict-
//    free, phase-1 b64 stores 2-way (free).
// ---------------------------------------------------------------------------
__global__ __launch_bounds__(512, 4) void edgeconv_fused(
    const float* __restrict__ ev, const float* __restrict__ W1,
    const float* __restrict__ b1, const float* __restrict__ W2,
    const float* __restrict__ b2, float* __restrict__ out) {
  const int b    = blockIdx.x >> 1;
  const int ph   = blockIdx.x & 1;
  const int tid  = threadIdx.x;
  const int lane = tid & 63;
  const int wave = tid >> 6;         // 0..7
  const int qd   = lane >> 4;        // 0..3
  const int c16  = lane & 15;

  __shared__ float sFeats[P_SZ][8];                     // 4 KB (full batch)
  __shared__ __align__(16) __bf16 sW1[16][32][8];       // 8 KB, k<16 half only
  __shared__ unsigned short sIdx[64][KNB];              // 2 KB (this block's pts)
  // union: 2 x sH1 double buffer (2 x 32768 B); KNN lists [8][16][64] f64
  // = 65536 B overlay exactly (disjoint lifetimes, barrier-separated).
  __shared__ __align__(16) unsigned char sU[2 * 32768];
  double* lists = (double*)sU;                          // [eighth][16][64]
  __bf16* buf0  = (__bf16*)sU;                          // sH1 buffer 0
  __bf16* buf1  = (__bf16*)(sU + 32768);                // sH1 buffer 1

  // ---- stage events + W1 frags (bias folded in at k=14; k<16 half only) ----
  if (tid < 2 * P_SZ)
    ((float4*)&sFeats[0][0])[tid] = ((const float4*)(ev + (size_t)b * P_SZ * 8))[tid];
  {   // 16 tiles x 32 rows (512 threads -> one each)
    const int t = tid >> 5, l32 = tid & 31;
    const int qq = l32 >> 4, cc = l32 & 15;
    const int n = t * 16 + cc;
    bf16x8 v;
#pragma unroll
    for (int j = 0; j < 8; ++j) {
      const int k = qq * 8 + j;
      float w = 0.0f;
      if (k < 2 * F_SZ) w = W1[k * H_SZ + n];
      else if (k == 2 * F_SZ) w = b1[n];   // bias row, edge supplies 1.0
      v[j] = (__bf16)w;
    }
    *(bf16x8*)&sW1[t][l32][0] = v;
  }
  __syncthreads();

  // ---- feats passthrough + mask channel (needs only sFeats) ----
  {
    const int pl = tid >> 3, ch = tid & 7;       // 64 pts x 8 ch
    const int pg = ph * 64 + pl;
    const float msk = sFeats[pg][7];
    float v;
    if (ch < 7) {
      float fv = sFeats[pg][ch];
      fv = fv > 0.0f ? fv : 0.2f * fv;
      v = (msk > 0.5f ? 1.0f : 0.0f) * fv;
    } else {
      v = msk;
    }
    out[((size_t)(b * P_SZ + pg)) * CH_OUT + H_SZ + ch] = v;
  }

  // ===================  KNN (f64 keys, bitonic merge tree)  =================
  // lane-point = ph*64 + lane; wave scans candidates wave*16..+15 (eighth).
  const int ip = ph * 64 + lane;
  const float xi = sFeats[ip][0], yi = sFeats[ip][1];

  double arr[16];
#pragma unroll
  for (int t = 0; t < 16; ++t) arr[t] = 1.0e300;

  // tiered sorted-insert scan: depth 8 for first 8 cands, depth 16 after.
#pragma unroll 1
  for (int cc = 0; cc < 8; ++cc) {
    const int j = wave * 16 + cc;              // wave-uniform -> LDS broadcast
    const float2 cj = *(const float2*)&sFeats[j][0];
    const float mj  = sFeats[j][7];
    const float dx = xi - cj.x, dy = yi - cj.y;
    const float d  = sqrtf(dx * dx + dy * dy);
    const float dd = (mj > 0.5f && j != ip) ? d : 3.0e38f;  // self excluded
    double key = (double)__float_as_uint(dd) * 128.0 + (double)j;  // exact
#pragma unroll
    for (int t = 0; t < 8; ++t) {
      const double lo = fmin(arr[t], key);
      key    = fmax(arr[t], key);
      arr[t] = lo;
    }
  }
#pragma unroll 1
  for (int cc = 8; cc < 16; ++cc) {
    const int j = wave * 16 + cc;
    const float2 cj = *(const float2*)&sFeats[j][0];
    const float mj  = sFeats[j][7];
    const float dx = xi - cj.x, dy = yi - cj.y;
    const float d  = sqrtf(dx * dx + dy * dy);
    const float dd = (mj > 0.5f && j != ip) ? d : 3.0e38f;
    double key = (double)__float_as_uint(dd) * 128.0 + (double)j;
#pragma unroll
    for (int t = 0; t < 16; ++t) {
      const double lo = fmin(arr[t], key);
      key    = fmax(arr[t], key);
      arr[t] = lo;
    }
  }

  // merge: half-cleaner (16 fmin) + 4-stage bitonic sort of bitonic seq.
  auto mergeList = [&](const double* src) {
    double oth[16];
#pragma unroll
    for (int t = 0; t < 16; ++t) oth[t] = src[t * 64 + lane];
#pragma unroll
    for (int t = 0; t < 16; ++t) arr[t] = fmin(arr[t], oth[15 - t]);
#pragma unroll
    for (int d = 8; d >= 1; d >>= 1) {
#pragma unroll
      for (int i = 0; i < 16; ++i) {
        if ((i & d) == 0) {
          const double lo = fmin(arr[i], arr[i + d]);
          arr[i + d] = fmax(arr[i], arr[i + d]);
          arr[i] = lo;
        }
      }
    }
  };
  auto publish = [&](int slot) {
#pragma unroll
    for (int t = 0; t < 16; ++t) lists[(slot * 16 + t) * 64 + lane] = arr[t];
  };

  if (wave >= 4) publish(wave);          // scan lists of eighths 4..7
  __syncthreads();
  if (wave < 4) {                        // stage A: {e, e+4}
    mergeList(&lists[((wave + 4) * 16) * 64]);
    publish(wave);
  }
  __syncthreads();
  if (wave == 0) mergeList(&lists[(1 * 16) * 64]);   // {0,1,4,5}
  if (wave == 2) {                                   // {2,3,6,7} -> slot 2
    mergeList(&lists[(3 * 16) * 64]);
    publish(2);
  }
  __syncthreads();
  if (wave == 0) {                       // stage C: full top-16, sorted asc
    mergeList(&lists[(2 * 16) * 64]);
#pragma unroll
    for (int t = 0; t < 16; ++t) {
      const unsigned long long kv = (unsigned long long)arr[t];
      sIdx[lane][t] = (unsigned short)(kv & 127);
    }
  }
  __syncthreads();   // sIdx ready; lists region free for sH1 buffers

  // ---- W2 B-fragments for 32x32x16: wave owns cols [wave*32, +32).
  // Per lane: col = wave*32 + (lane&31), k = kk*16 + (lane>>5)*8 + j.
  // 16 frags x 4 VGPR = 64 regs; loaded after KNN (arr/oth dead).
  const int wcol  = wave * 32 + (lane & 31);
  const int khalf = (lane >> 5) * 8;
  bf16x8 w2f[16];
#pragma unroll
  for (int kk = 0; kk < 16; ++kk) {
#pragma unroll
    for (int j = 0; j < 8; ++j)
      w2f[kk][j] = (__bf16)W2[(kk * 16 + khalf + j) * H_SZ + wcol];
  }
  const float b2v = b2[wcol];

  // ---- Phase 1 (transposed GEMM1) for iteration it1 into buffer sH1w ----
  auto phase1 = [&](int it1, __bf16* __restrict__ sH1w) {
    const int pl = it1 * 4 + (wave >> 1);  // local point 0..63
    const int pg = ph * 64 + pl;           // global row in sFeats
    const int hh = wave & 1;               // W1-tile half
    const float* cf = &sFeats[pg][0];
    // predicated gather: only qd<2 lanes use neighbor feats (qd>=2 edges = 0)
    float4 nf0 = {0.0f, 0.0f, 0.0f, 0.0f}, nf1 = {0.0f, 0.0f, 0.0f, 0.0f};
    if (qd < 2) {
      const int nb = sIdx[pl][c16];
      nf0 = *(const float4*)&sFeats[nb][0];
      nf1 = *(const float4*)&sFeats[nb][4];
    }
    const float nfv[8] = {nf0.x, nf0.y, nf0.z, nf0.w, nf1.x, nf1.y, nf1.z, nf1.w};
    float ed[8];
    if (qd == 0) {        // k = 0..7: central[0..6], (neigh-central)[0]
#pragma unroll
      for (int j = 0; j < 7; ++j) ed[j] = cf[j];
      ed[7] = nfv[0] - cf[0];
    } else if (qd == 1) { // k = 8..15: (n-c)[1..6], bias-1.0 at k=14, pad
#pragma unroll
      for (int j = 0; j < 6; ++j) ed[j] = nfv[j + 1] - cf[j + 1];
      ed[6] = 1.0f; ed[7] = 0.0f;
    } else {              // k = 16..31: zero pad (lanes>=32 A-frag don't-care)
#pragma unroll
      for (int j = 0; j < 8; ++j) ed[j] = 0.0f;
    }
    bf16x8 af;
#pragma unroll
    for (int j = 0; j < 8; ++j) af[j] = (__bf16)ed[j];

#pragma unroll
    for (int t = 0; t < 8; ++t) {
      const int tt = hh * 8 + t;
      // lanes >=32: same-address broadcast read; value is don't-care (af==0)
      bf16x8 w1t = *(const bf16x8*)&sW1[tt][lane & 31][0];
      f32x4 acc = {0.0f, 0.0f, 0.0f, 0.0f};
      acc = __builtin_amdgcn_mfma_f32_16x16x32_bf16(w1t, af, acc, 0, 0, 0);
      bf16x4 hv;
#pragma unroll
      for (int rr = 0; rr < 4; ++rr) {
        float h = acc[rr];
        h = h > 0.0f ? h : 0.0f;
        hv[rr] = (__bf16)h;
      }
      // chunk-major: n = tt*16 + qd*4 + rr -> kc = tt*2 + (qd>>1), off = (qd&1)*4
      const int kc = tt * 2 + (qd >> 1);
      *(bf16x4*)&sH1w[(((size_t)(wave >> 1) * 32 + kc) * 16 + c16) * 8 + (qd & 1) * 4] = hv;
    }
  };

  // ---- Phase-2 epilogue for one group's acc (points {g*2, g*2+1}) ----
  // C/D: col = lane&31, row = (reg&3)+8*(reg>>2)+4*(lane>>5):
  //   ptA rows 0..15 in regs 0..7 (split across lane halves),
  //   ptB rows 16..31 in regs 8..15 -> one shfl_xor(32) per point-sum.
  auto epi = [&](const f32x16& acc, int it2, int g) {
    float sA = 0.0f, sB = 0.0f;
#pragma unroll
    for (int r = 0; r < 8; ++r) {
      const float h = acc[r] + b2v;
      sA += (h > 0.0f ? h : 0.0f);
    }
#pragma unroll
    for (int r = 8; r < 16; ++r) {
      const float h = acc[r] + b2v;
      sB += (h > 0.0f ? h : 0.0f);
    }
    sA += __shfl_xor(sA, 32, 64);       // combine the two lane-half row sets
    sB += __shfl_xor(sB, 32, 64);
    const int pi  = lane >> 5;          // lanes<32 store ptA, lanes>=32 ptB
    const float s = pi ? sB : sA;
    const int ptg = ph * 64 + it2 * 4 + g * 2 + pi;
    const float msk  = sFeats[ptg][7];
    const float keep = (msk > 0.5f) ? 1.0f : 0.0f;
    const float agg = s * (1.0f / 16.0f);
    const float o = agg > 0.0f ? agg : 0.2f * agg;
    out[((size_t)(b * P_SZ + ptg)) * CH_OUT + wave * 32 + (lane & 31)] = keep * o;
  };

  // =================  pipelined main loop: 1 barrier / iter  =================
  phase1(0, buf0);
  __syncthreads();
#pragma unroll 1
  for (int it = 0; it < 16; ++it) {
    const __bf16* rd = (it & 1) ? buf1 : buf0;
    __bf16* wr = (it & 1) ? buf0 : buf1;

    // ---- fused phase-2 k-loop: both groups, 2 independent MFMA chains ----
    // A-frag: m = lane&31 (pt,nbr), kc = kk*2 + (lane>>5).
    f32x16 accA = {}, accB = {};
    {
      const int appA = (lane >> 4) & 1;       // group 0: points 0,1
      const int appB = 2 + appA;              // group 1: points 2,3
      const int anb  = lane & 15;
      const int kho  = lane >> 5;
#pragma unroll
      for (int kk = 0; kk < 16; ++kk) {
        const int kc = kk * 2 + kho;
        bf16x8 aA = *(const bf16x8*)&rd[(((size_t)appA * 32 + kc) * 16 + anb) * 8];
        bf16x8 aB = *(const bf16x8*)&rd[(((size_t)appB * 32 + kc) * 16 + anb) * 8];
        accA = __builtin_amdgcn_mfma_f32_32x32x16_bf16(aA, w2f[kk], accA, 0, 0, 0);
        accB = __builtin_amdgcn_mfma_f32_32x32x16_bf16(aB, w2f[kk], accB, 0, 0, 0);
      }
    }

    epi(accA, it, 0);                  // frees accA before phase1's liveness
    if (it < 15) phase1(it + 1, wr);   // VALU/LDS-heavy, fills other buffer
    epi(accB, it, 1);

    if (it < 15) __syncthreads();      // wr complete before next iter reads it
  }
}

// ---------------------------------------------------------------------------
extern "C" void kernel_launch(void* const* d_in, const int* in_sizes, int n_in,
                              void* d_out, int out_size, void* d_ws, size_t ws_size,
                              hipStream_t stream) {
  const float* ev = (const float*)d_in[0];
  const float* W1 = (const float*)d_in[1];
  const float* b1 = (const float*)d_in[2];
  const float* W2 = (const float*)d_in[3];
  const float* b2 = (const float*)d_in[4];
  float* out = (float*)d_out;

  edgeconv_fused<<<B_SZ * 2, 512, 0, stream>>>(ev, W1, b1, W2, b2, out);
}